// Round 3
// baseline (409.994 us; speedup 1.0000x reference)
//
#include <hip/hip_runtime.h>
#include <hip/hip_bf16.h>

#define N_PIX 16384
#define W_ 128

typedef __attribute__((ext_vector_type(8))) unsigned short ushort8_t;
typedef __attribute__((ext_vector_type(4))) unsigned short ushort4_t;
typedef __attribute__((ext_vector_type(8))) __bf16 bf16x8;
typedef __attribute__((ext_vector_type(4))) float f32x4;

__device__ inline float bf2f(unsigned short u) {
    return __uint_as_float(((unsigned)u) << 16);
}
__device__ inline unsigned short f2bf(float f) {
    __hip_bfloat16 h = __float2bfloat16(f);
    return *(unsigned short*)&h;
}

// ---------------------------------------------------------------------------
// pack both f32 conv weights -> bf16 (linear). 110592 elems each, /4 per
// thread = 108 blocks per weight; grid 216.
// ---------------------------------------------------------------------------
__global__ __launch_bounds__(256) void k_pack_w(
    const float* __restrict__ wa, const float* __restrict__ wb,
    unsigned short* __restrict__ oa, unsigned short* __restrict__ ob)
{
    const int blk = blockIdx.x;
    const float* w = (blk < 108) ? wa : wb;
    unsigned short* o = (blk < 108) ? oa : ob;
    const int i = ((blk % 108) * 256 + threadIdx.x) * 4;
    float4 v = *(const float4*)(w + i);
    ushort4_t s;
    s[0] = f2bf(v.x); s[1] = f2bf(v.y); s[2] = f2bf(v.z); s[3] = f2bf(v.w);
    *(ushort4_t*)(o + i) = s;
}

// ---------------------------------------------------------------------------
// conv1x1 via bf16 MFMA, round 6: merged x+ctx launch (grid y 0..7), W read
// from global bf16 (L2-hot) with per-oc register hoist of all 18 A-fragments
// (72 VGPRs) -> no W LDS, no inner barriers. LDS = X tile only (51.2 KB,
// 2 blocks/CU). Wave tile: M=48 (wo) x N=64 (wp); 6 oc chunks of 96 rows.
// ---------------------------------------------------------------------------
__global__ __launch_bounds__(256, 2) void k_conv_mfma(
    const float* __restrict__ x, const float* __restrict__ ctx,
    const unsigned short* __restrict__ wx, const unsigned short* __restrict__ wc,
    unsigned short* __restrict__ ox, unsigned short* __restrict__ octx)
{
    const int p0 = blockIdx.x * 128;
    const int bb = blockIdx.y;            // 0..7 (or 0..3 in serial mode)
    const int b  = bb & 3;
    const bool isx = bb < 4;
    const float* inb = (isx ? x : ctx) + (long)b * 192 * N_PIX;
    const unsigned short* wbf = isx ? wx : wc;
    unsigned short* ob = (isx ? ox : octx) + (long)b * 576 * N_PIX;

    __shared__ unsigned short Xl[128 * 200];   // 51.2 KB

    const int tid  = threadIdx.x;
    const int lane = tid & 63;
    const int wid  = tid >> 6;
    const int wo   = wid >> 1;
    const int wp   = wid & 1;
    const int l15  = lane & 15;
    const int lq   = lane >> 4;

    {   // stage X tile transposed [p][k], f32 -> bf16
        const int p = tid & 127, kh = tid >> 7;
        #pragma unroll
        for (int seg = 0; seg < 12; seg++) {
            ushort8_t pk;
            #pragma unroll
            for (int j = 0; j < 8; j++)
                pk[j] = f2bf(inb[(long)(kh * 96 + seg * 8 + j) * N_PIX + p0 + p]);
            *(ushort8_t*)&Xl[p * 200 + kh * 96 + seg * 8] = pk;
        }
    }
    __syncthreads();   // only barrier in the kernel

    #pragma unroll 1
    for (int oc = 0; oc < 6; oc++) {
        // hoist this chunk's W fragments into registers (one L2 burst,
        // covered by the 72 MFMAs below + co-resident block)
        bf16x8 af[3][6];
        #pragma unroll
        for (int mt = 0; mt < 3; mt++)
            #pragma unroll
            for (int kc = 0; kc < 6; kc++)
                af[mt][kc] = *(const bf16x8*)(wbf +
                    (long)(oc * 96 + wo * 48 + mt * 16 + l15) * 192 + kc * 32 + lq * 8);

        f32x4 acc[3][4];
        const f32x4 zero = {0.f, 0.f, 0.f, 0.f};
        #pragma unroll
        for (int i = 0; i < 3; i++)
            #pragma unroll
            for (int j = 0; j < 4; j++) acc[i][j] = zero;

        #pragma unroll
        for (int kc = 0; kc < 6; kc++) {
            bf16x8 bfv[4];
            #pragma unroll
            for (int nt = 0; nt < 4; nt++)
                bfv[nt] = *(const bf16x8*)&Xl[(wp * 64 + nt * 16 + l15) * 200 + kc * 32 + lq * 8];
            #pragma unroll
            for (int mt = 0; mt < 3; mt++)
                #pragma unroll
                for (int nt = 0; nt < 4; nt++)
                    acc[mt][nt] = __builtin_amdgcn_mfma_f32_16x16x32_bf16(
                        af[mt][kc], bfv[nt], acc[mt][nt], 0, 0, 0);
        }
        #pragma unroll
        for (int mt = 0; mt < 3; mt++) {
            #pragma unroll
            for (int r = 0; r < 4; r++) {
                int o = oc * 96 + wo * 48 + mt * 16 + lq * 4 + r;
                long base = (long)o * N_PIX + p0 + wp * 64 + l15;
                #pragma unroll
                for (int nt = 0; nt < 4; nt++)
                    ob[base + nt * 16] = f2bf(acc[mt][nt][r]);
            }
        }
    }
}

// ---------------------------------------------------------------------------
// depthwise 3x3, pad 1, bf16 -> bf16, merged x+ctx (grid y 0..4607):
// block = 16 rows x 128 cols of one map; 18x128 halo staged in LDS.
// ---------------------------------------------------------------------------
__global__ __launch_bounds__(256) void k_dwconv(
    const unsigned short* __restrict__ tx, const unsigned short* __restrict__ tc,
    const float* __restrict__ wxd, const float* __restrict__ wcd,
    unsigned short* __restrict__ qx, unsigned short* __restrict__ qc)
{
    const int mz = blockIdx.y;
    const int br = (mz >= 2304) ? 1 : 0;
    const int m  = mz - br * 2304;          // b*576 + ch
    const int ch = m % 576;
    const int y0 = blockIdx.x * 16;
    const unsigned short* ip = (br ? tc : tx) + (long)m * N_PIX;
    const float* wp = (br ? wcd : wxd) + ch * 9;
    unsigned short* op = (br ? qc : qx) + (long)m * N_PIX;

    __shared__ unsigned short Ll[18][136];

    const int tid = threadIdx.x;
    #pragma unroll
    for (int idx = tid; idx < 288; idx += 256) {
        int lr = idx >> 4, lc = (idx & 15) * 8;
        int gy = y0 - 1 + lr;
        ushort8_t v;
        #pragma unroll
        for (int j = 0; j < 8; j++) v[j] = 0;
        if ((unsigned)gy <= 127u)
            v = *(const ushort8_t*)(ip + gy * W_ + lc);
        *(ushort8_t*)&Ll[lr][lc] = v;
    }
    float wv[9];
    #pragma unroll
    for (int i = 0; i < 9; i++) wv[i] = wp[i];
    __syncthreads();

    const int r  = tid >> 4;
    const int xg = (tid & 15) * 8;

    float o[8];
    #pragma unroll
    for (int j = 0; j < 8; j++) o[j] = 0.f;

    #pragma unroll
    for (int dy = 0; dy < 3; dy++) {
        const unsigned short* lrow = &Ll[r + dy][0];
        float c[10];
        c[0] = (xg == 0) ? 0.f : bf2f(lrow[xg - 1]);
        ushort8_t mid = *(const ushort8_t*)&lrow[xg];
        #pragma unroll
        for (int j = 0; j < 8; j++) c[1 + j] = bf2f(mid[j]);
        c[9] = (xg == 120) ? 0.f : bf2f(lrow[xg + 8]);
        const float w0 = wv[dy * 3], w1 = wv[dy * 3 + 1], w2 = wv[dy * 3 + 2];
        #pragma unroll
        for (int j = 0; j < 8; j++)
            o[j] = fmaf(w0, c[j], fmaf(w1, c[j + 1], fmaf(w2, c[j + 2], o[j])));
    }
    ushort8_t res;
    #pragma unroll
    for (int j = 0; j < 8; j++) res[j] = f2bf(o[j]);
    *(ushort8_t*)(op + (y0 + r) * W_ + xg) = res;
}

// ---------------------------------------------------------------------------
// gram + norms via MFMA (unchanged)
// ---------------------------------------------------------------------------
__global__ __launch_bounds__(256) void k_gram_mfma(
    const unsigned short* __restrict__ qkv_x,
    const unsigned short* __restrict__ qkv_c,
    float* __restrict__ S, float* __restrict__ qn, float* __restrict__ kn)
{
    const int attn = blockIdx.z;
    const int bh   = blockIdx.y;
    const int b = bh >> 2, h = bh & 3;
    const unsigned short* qb =
        (attn == 0 ? qkv_x : qkv_c) + ((long)b * 576 + h * 48) * N_PIX;
    const unsigned short* kb =
        (attn == 0 ? qkv_c : qkv_x) + ((long)b * 576 + 192 + h * 48) * N_PIX;

    __shared__ float Sl[48 * 49];
    __shared__ float qnl[48], knl[48];

    const int tid = threadIdx.x;
    for (int i = tid; i < 48 * 49; i += 256) Sl[i] = 0.f;
    if (tid < 48) { qnl[tid] = 0.f; knl[tid] = 0.f; }
    __syncthreads();

    const int lane = tid & 63, wid = tid >> 6;
    const int l15 = lane & 15, lq = lane >> 4;
    const long nbase = (long)blockIdx.x * 1024 + wid * 256;

    f32x4 acc[3][3], aq[3], ak[3];
    const f32x4 zero = {0.f, 0.f, 0.f, 0.f};
    #pragma unroll
    for (int i = 0; i < 3; i++) {
        aq[i] = zero; ak[i] = zero;
        #pragma unroll
        for (int j = 0; j < 3; j++) acc[i][j] = zero;
    }

    for (int ks = 0; ks < 8; ks++) {
        const long ns = nbase + ks * 32;
        bf16x8 af[3], bfv[3];
        #pragma unroll
        for (int mt = 0; mt < 3; mt++)
            af[mt] = *(const bf16x8*)(qb + (long)(mt * 16 + l15) * N_PIX + ns + lq * 8);
        #pragma unroll
        for (int nt = 0; nt < 3; nt++)
            bfv[nt] = *(const bf16x8*)(kb + (long)(nt * 16 + l15) * N_PIX + ns + lq * 8);
        #pragma unroll
        for (int mt = 0; mt < 3; mt++)
            #pragma unroll
            for (int nt = 0; nt < 3; nt++)
                acc[mt][nt] = __builtin_amdgcn_mfma_f32_16x16x32_bf16(
                    af[mt], bfv[nt], acc[mt][nt], 0, 0, 0);
        #pragma unroll
        for (int mt = 0; mt < 3; mt++)
            aq[mt] = __builtin_amdgcn_mfma_f32_16x16x32_bf16(af[mt], af[mt], aq[mt], 0, 0, 0);
        #pragma unroll
        for (int nt = 0; nt < 3; nt++)
            ak[nt] = __builtin_amdgcn_mfma_f32_16x16x32_bf16(bfv[nt], bfv[nt], ak[nt], 0, 0, 0);
    }

    #pragma unroll
    for (int mt = 0; mt < 3; mt++)
        #pragma unroll
        for (int nt = 0; nt < 3; nt++)
            #pragma unroll
            for (int r = 0; r < 4; r++)
                atomicAdd(&Sl[(mt * 16 + lq * 4 + r) * 49 + nt * 16 + l15],
                          acc[mt][nt][r]);
    #pragma unroll
    for (int mt = 0; mt < 3; mt++)
        #pragma unroll
        for (int r = 0; r < 4; r++)
            if (l15 == lq * 4 + r) {
                atomicAdd(&qnl[mt * 16 + l15], aq[mt][r]);
                atomicAdd(&knl[mt * 16 + l15], ak[mt][r]);
            }
    __syncthreads();

    float* Sg = S + (long)(attn * 16 + bh) * 2304;
    float* qg = qn + (long)(attn * 16 + bh) * 48;
    float* kg = kn + (long)(attn * 16 + bh) * 48;
    for (int i = tid; i < 2304; i += 256) {
        int row = i / 48, col = i - row * 48;
        atomicAdd(&Sg[i], Sl[row * 49 + col]);
    }
    if (tid < 48) atomicAdd(&qg[tid], qnl[tid]);
    else if (tid < 96) atomicAdd(&kg[tid - 48], knl[tid - 48]);
}

// ---------------------------------------------------------------------------
// softmax (unchanged)
// ---------------------------------------------------------------------------
__global__ __launch_bounds__(192) void k_softmax(
    const float* __restrict__ S, const float* __restrict__ qn,
    const float* __restrict__ kn, const float* __restrict__ temp,
    float* __restrict__ P)
{
    const int attn = blockIdx.x, b = blockIdx.y;
    const int r = threadIdx.x;
    const int h = r / 48, c = r % 48;
    const int bh = b * 4 + h;
    const float t = temp[h];
    const float* Srow = S + ((long)(attn * 16 + bh) * 48 + c) * 48;
    const float* knp  = kn + (long)(attn * 16 + bh) * 48;
    const float qc = fmaxf(sqrtf(qn[(long)(attn * 16 + bh) * 48 + c]), 1e-12f);
    float lg[48];
    float mx = -1e30f;
    #pragma unroll
    for (int d = 0; d < 48; d++) {
        float kd = fmaxf(sqrtf(knp[d]), 1e-12f);
        lg[d] = Srow[d] / (qc * kd) * t;
        mx = fmaxf(mx, lg[d]);
    }
    float sum = 0.f;
    #pragma unroll
    for (int d = 0; d < 48; d++) { lg[d] = __expf(lg[d] - mx); sum += lg[d]; }
    const float inv = 1.f / sum;
    float* Pp = P + (((long)(attn * 4 + b) * 4 + h) * 48 + c) * 48;
    #pragma unroll
    for (int d = 0; d < 48; d++) Pp[d] = lg[d] * inv;
}

// ---------------------------------------------------------------------------
// W2[attn][b][o][h*48+d] = sum_c po[o][h*48+c] * P[attn][b][h][c][d]  (bf16)
// ---------------------------------------------------------------------------
__global__ __launch_bounds__(192) void k_w2(
    const float* __restrict__ P, const float* __restrict__ x_po,
    const float* __restrict__ ctx_po, unsigned short* __restrict__ W2)
{
    const int h = blockIdx.x, b = blockIdx.y, attn = blockIdx.z;
    const float* po = (attn == 0) ? ctx_po : x_po;
    __shared__ float Pl[48][48];
    const float* Pp = P + ((long)(attn * 4 + b) * 4 + h) * 2304;
    for (int it = 0; it < 12; it++) {
        int idx = it * 192 + threadIdx.x;
        Pl[idx / 48][idx % 48] = Pp[idx];
    }
    __syncthreads();
    const int o = threadIdx.x;
    float acc[48];
    #pragma unroll
    for (int d = 0; d < 48; d++) acc[d] = 0.f;
    for (int c = 0; c < 48; c++) {
        float pv = po[(long)o * 192 + h * 48 + c];
        #pragma unroll
        for (int d = 0; d < 48; d++)
            acc[d] = fmaf(pv, Pl[c][d], acc[d]);
    }
    unsigned short* wp = W2 + ((long)(attn * 4 + b) * 192 + o) * 192 + h * 48;
    #pragma unroll
    for (int d = 0; d < 48; d++) wp[d] = f2bf(acc[d]);
}

// ---------------------------------------------------------------------------
// final GEMM via MFMA: 128-px tile, W2 per-oc register hoist, grid (128,8).
// ---------------------------------------------------------------------------
__global__ __launch_bounds__(256, 2) void k_gemm_v(
    const unsigned short* __restrict__ qkv_x,
    const unsigned short* __restrict__ qkv_c,
    const unsigned short* __restrict__ W2bf,   // [attn][b][192][192] bf16
    float* __restrict__ out)
{
    const int p0 = blockIdx.x * 128;
    const int z  = blockIdx.y;
    const int br = z >> 2, b = z & 3;
    const unsigned short* v =
        (br == 0 ? qkv_x : qkv_c) + (long)b * 576 * N_PIX + 384L * N_PIX;
    const unsigned short* wb =
        W2bf + ((long)((br == 0 ? 1 : 0) * 4 + b)) * 36864;
    float* ob = out + (long)br * 12582912 + (long)b * 192 * N_PIX;

    __shared__ unsigned short Xl[128 * 200];

    const int tid  = threadIdx.x;
    const int lane = tid & 63;
    const int wid  = tid >> 6;
    const int wo   = wid >> 1;
    const int wp   = wid & 1;
    const int l15  = lane & 15;
    const int lq   = lane >> 4;

    {   // stage V tile transposed [p][k]
        const int p = tid & 127, kh = tid >> 7;
        #pragma unroll
        for (int seg = 0; seg < 12; seg++) {
            ushort8_t pk;
            #pragma unroll
            for (int j = 0; j < 8; j++)
                pk[j] = v[(long)(kh * 96 + seg * 8 + j) * N_PIX + p0 + p];
            *(ushort8_t*)&Xl[p * 200 + kh * 96 + seg * 8] = pk;
        }
    }
    __syncthreads();

    #pragma unroll 1
    for (int oc = 0; oc < 2; oc++) {
        bf16x8 af[3][6];
        #pragma unroll
        for (int mt = 0; mt < 3; mt++)
            #pragma unroll
            for (int kc = 0; kc < 6; kc++)
                af[mt][kc] = *(const bf16x8*)(wb +
                    (long)(oc * 96 + wo * 48 + mt * 16 + l15) * 192 + kc * 32 + lq * 8);

        f32x4 acc[3][4];
        const f32x4 zero = {0.f, 0.f, 0.f, 0.f};
        #pragma unroll
        for (int i = 0; i < 3; i++)
            #pragma unroll
            for (int j = 0; j < 4; j++) acc[i][j] = zero;

        #pragma unroll
        for (int kc = 0; kc < 6; kc++) {
            bf16x8 bfv[4];
            #pragma unroll
            for (int nt = 0; nt < 4; nt++)
                bfv[nt] = *(const bf16x8*)&Xl[(wp * 64 + nt * 16 + l15) * 200 + kc * 32 + lq * 8];
            #pragma unroll
            for (int mt = 0; mt < 3; mt++)
                #pragma unroll
                for (int nt = 0; nt < 4; nt++)
                    acc[mt][nt] = __builtin_amdgcn_mfma_f32_16x16x32_bf16(
                        af[mt][kc], bfv[nt], acc[mt][nt], 0, 0, 0);
        }
        #pragma unroll
        for (int mt = 0; mt < 3; mt++) {
            #pragma unroll
            for (int r = 0; r < 4; r++) {
                int o = oc * 96 + wo * 48 + mt * 16 + lq * 4 + r;
                long base = (long)o * N_PIX + p0 + wp * 64 + l15;
                #pragma unroll
                for (int nt = 0; nt < 4; nt++)
                    ob[base + nt * 16] = acc[mt][nt][r];
            }
        }
    }
}

// ---------------------------------------------------------------------------
extern "C" void kernel_launch(void* const* d_in, const int* in_sizes, int n_in,
                              void* d_out, int out_size, void* d_ws, size_t ws_size,
                              hipStream_t stream) {
    (void)in_sizes; (void)n_in; (void)out_size;
    const float* x       = (const float*)d_in[0];
    const float* ctx     = (const float*)d_in[1];
    const float* x_qkv_w = (const float*)d_in[2];
    const float* x_dw_w  = (const float*)d_in[3];
    const float* x_po_w  = (const float*)d_in[4];
    const float* c_qkv_w = (const float*)d_in[5];
    const float* c_dw_w  = (const float*)d_in[6];
    const float* c_po_w  = (const float*)d_in[7];
    const float* temp    = (const float*)d_in[8];
    float* out = (float*)d_out;

    const long QKV = 37748736L;                  // 4*576*16384 elements
    unsigned short* qkv_x16 = (unsigned short*)d_ws;
    unsigned short* qkv_c16 = qkv_x16 + QKV;
    float* S  = (float*)(qkv_c16 + QKV);         // 2*16*48*48
    float* qn = S + 73728;
    float* kn = qn + 1536;
    float* P  = kn + 1536;
    unsigned short* W2bf = (unsigned short*)(P + 73728);   // 2*4*192*192 bf16

    // conv scratch for the x branch lives in d_out (fully overwritten by
    // k_gemm_v at the end). Packed bf16 conv weights in d_out's tail.
    unsigned short* tmp_x = (unsigned short*)d_out;
    unsigned short* wx16  = (unsigned short*)d_out + QKV;
    unsigned short* wc16  = wx16 + 110592;

    k_pack_w<<<dim3(216), 256, 0, stream>>>(x_qkv_w, c_qkv_w, wx16, wc16);

    // ctx conv scratch: aliases S..end-of-ws (dead until dwconv completes;
    // memset of S happens after dwconv). Needs ws >= 2*QKV*2 + QKV*2 bytes.
    const size_t ws_needed = (size_t)QKV * 2 * 3;   // 301,989,888 B
    if (ws_size >= ws_needed) {
        // merged path: both convs in one launch, both dwconvs in one launch
        unsigned short* tmp_c = (unsigned short*)S;
        k_conv_mfma<<<dim3(128, 8), 256, 0, stream>>>(
            x, ctx, wx16, wc16, tmp_x, tmp_c);
        k_dwconv<<<dim3(8, 4608), 256, 0, stream>>>(
            tmp_x, tmp_c, x_dw_w, c_dw_w, qkv_x16, qkv_c16);
    } else {
        // serial fallback: reuse tmp_x for both branches
        k_conv_mfma<<<dim3(128, 4), 256, 0, stream>>>(
            x, x, wx16, wx16, tmp_x, tmp_x);
        k_dwconv<<<dim3(8, 2304), 256, 0, stream>>>(
            tmp_x, tmp_x, x_dw_w, x_dw_w, qkv_x16, qkv_x16);
        k_conv_mfma<<<dim3(128, 4), 256, 0, stream>>>(
            ctx, ctx, wc16, wc16, tmp_x, tmp_x);
        k_dwconv<<<dim3(8, 2304), 256, 0, stream>>>(
            tmp_x, tmp_x, c_dw_w, c_dw_w, qkv_c16, qkv_c16);
    }

    // S/qn/kn zero AFTER dwconv (S region aliased tmp_c in merged mode)
    hipMemsetAsync(S, 0, (73728 + 1536 + 1536) * sizeof(float), stream);

    k_gram_mfma<<<dim3(16, 16, 2), 256, 0, stream>>>(qkv_x16, qkv_c16, S, qn, kn);
    k_softmax<<<dim3(2, 4), dim3(192), 0, stream>>>(S, qn, kn, temp, P);
    k_w2<<<dim3(4, 4, 2), dim3(192), 0, stream>>>(P, x_po_w, c_po_w, W2bf);

    k_gemm_v<<<dim3(128, 8), 256, 0, stream>>>(qkv_x16, qkv_c16, W2bf, out);
}